// Round 1
// baseline (320.430 us; speedup 1.0000x reference)
//
#include <hip/hip_runtime.h>

#define T_SEQ 2048
#define BATCH 4096
#define NH    3
#define UF    16   // prefetch/unroll block (16 KB in flight per wave)

struct Out3 { float a, b, c; };

// One thread per batch element. 64 blocks x 64 threads = 64 waves spread
// across CUs; each wave owns its SIMD (issue-bound regime, so spread wide).
__global__ __launch_bounds__(64, 1) void rnn_fused(
    const float* __restrict__ x,    // [T, B, 4]
    const float* __restrict__ h0,   // [B, 3]
    const float* __restrict__ Wih,  // [3, 4]
    const float* __restrict__ Whh,  // [3, 3]
    const float* __restrict__ bih,  // [3]
    const float* __restrict__ bhh,  // [3]
    float* __restrict__ out)        // [T, B, 3] then [B, 3]
{
    const int b = blockIdx.x * 64 + threadIdx.x;

    // Uniform weight loads -> SGPRs via s_load
    const float w00 = Wih[0], w01 = Wih[1], w02 = Wih[2],  w03 = Wih[3];
    const float w10 = Wih[4], w11 = Wih[5], w12 = Wih[6],  w13 = Wih[7];
    const float w20 = Wih[8], w21 = Wih[9], w22 = Wih[10], w23 = Wih[11];
    const float a00 = Whh[0], a01 = Whh[1], a02 = Whh[2];
    const float a10 = Whh[3], a11 = Whh[4], a12 = Whh[5];
    const float a20 = Whh[6], a21 = Whh[7], a22 = Whh[8];
    const float bb0 = bih[0] + bhh[0];
    const float bb1 = bih[1] + bhh[1];
    const float bb2 = bih[2] + bhh[2];

    float h0r = h0[b * 3 + 0];
    float h1r = h0[b * 3 + 1];
    float h2r = h0[b * 3 + 2];

    const float4* __restrict__ xb = (const float4*)x;  // [T][B] float4
    Out3* __restrict__ ob = (Out3*)out;                // [T][B] 12B

    // One RNN step: 12 FMA (x-proj, h-independent) + 9 FMA + 3 max.
    // Chain h->h is 3 FMA + 1 max (~16 cyc) << issue time, so ILP is fine.
#define STEP(XV, TT) do {                                                     \
        float p0 = fmaf(w00, (XV).x, fmaf(w01, (XV).y,                        \
                   fmaf(w02, (XV).z, fmaf(w03, (XV).w, bb0))));               \
        float p1 = fmaf(w10, (XV).x, fmaf(w11, (XV).y,                        \
                   fmaf(w12, (XV).z, fmaf(w13, (XV).w, bb1))));               \
        float p2 = fmaf(w20, (XV).x, fmaf(w21, (XV).y,                        \
                   fmaf(w22, (XV).z, fmaf(w23, (XV).w, bb2))));               \
        float t0 = fmaf(a00, h0r, fmaf(a01, h1r, fmaf(a02, h2r, p0)));        \
        float t1 = fmaf(a10, h0r, fmaf(a11, h1r, fmaf(a12, h2r, p1)));        \
        float t2 = fmaf(a20, h0r, fmaf(a21, h1r, fmaf(a22, h2r, p2)));        \
        h0r = fmaxf(t0, 0.0f);                                                \
        h1r = fmaxf(t1, 0.0f);                                                \
        h2r = fmaxf(t2, 0.0f);                                                \
        ob[(size_t)(TT) * BATCH + b] = Out3{h0r, h1r, h2r};                   \
    } while (0)

    // Double-buffered prefetch: named buffers + full unroll => all indices
    // compile-time constant => stays in VGPRs (no scratch).
    float4 bufA[UF], bufB[UF];

#pragma unroll
    for (int u = 0; u < UF; ++u)
        bufA[u] = xb[(size_t)u * BATCH + b];

    constexpr int NB = T_SEQ / UF;  // 128 blocks, even => clean 2x pipeline
#pragma unroll 1
    for (int blk = 0; blk < NB; blk += 2) {
        // prefetch block blk+1 into bufB (in flight during bufA compute)
#pragma unroll
        for (int u = 0; u < UF; ++u)
            bufB[u] = xb[((size_t)(blk + 1) * UF + u) * BATCH + b];

#pragma unroll
        for (int u = 0; u < UF; ++u) {
            STEP(bufA[u], blk * UF + u);
        }

        // prefetch block blk+2 into bufA
        if (blk + 2 < NB) {
#pragma unroll
            for (int u = 0; u < UF; ++u)
                bufA[u] = xb[((size_t)(blk + 2) * UF + u) * BATCH + b];
        }

#pragma unroll
        for (int u = 0; u < UF; ++u) {
            STEP(bufB[u], (blk + 1) * UF + u);
        }
    }
#undef STEP

    // h_last = outs[T-1] appended at offset T*B*3
    Out3* lastp = (Out3*)(out + (size_t)T_SEQ * BATCH * NH);
    lastp[b] = Out3{h0r, h1r, h2r};
}

extern "C" void kernel_launch(void* const* d_in, const int* in_sizes, int n_in,
                              void* d_out, int out_size, void* d_ws, size_t ws_size,
                              hipStream_t stream) {
    const float* x   = (const float*)d_in[0];
    const float* h0  = (const float*)d_in[1];
    const float* Wih = (const float*)d_in[2];
    const float* Whh = (const float*)d_in[3];
    const float* bih = (const float*)d_in[4];
    const float* bhh = (const float*)d_in[5];
    float* out = (float*)d_out;

    rnn_fused<<<BATCH / 64, 64, 0, stream>>>(x, h0, Wih, Whh, bih, bhh, out);
}

// Round 2
// 304.673 us; speedup vs baseline: 1.0517x; 1.0517x over previous
//
#include <hip/hip_runtime.h>

#define T_SEQ  2048
#define BATCH  4096
#define CHUNK  8                    // timesteps per pipeline stage
#define NCHUNK (T_SEQ / CHUNK)      // 256
#define RING   4                    // chunks resident in LDS ring
// LDS ring: RING*CHUNK slots x 64 lanes x 16 B = 32 KB

struct Out3 { float a, b, c; };
typedef float v4f __attribute__((ext_vector_type(4)));

#define AS1c(p) ((const __attribute__((address_space(1))) void*)(p))
#define AS3(p)  ((__attribute__((address_space(3))) void*)(p))

// One thread per batch element; 64 blocks x 64 threads = 64 waves, one per
// SIMD across 64 CUs. The serial t-loop is pipelined through an LDS ring:
// global_load_lds (no VGPR cost, cannot be sunk by the scheduler) stages
// chunk ci+3 while chunk ci computes; counted vmcnt keeps 3 chunks (24
// loads, ~1250 cyc of compute) in flight -- covers ~900 cyc HBM latency.
__global__ __launch_bounds__(64, 1) void rnn_fused(
    const float* __restrict__ x,    // [T, B, 4]
    const float* __restrict__ h0,   // [B, 3]
    const float* __restrict__ Wih,  // [3, 4]
    const float* __restrict__ Whh,  // [3, 3]
    const float* __restrict__ bih,  // [3]
    const float* __restrict__ bhh,  // [3]
    float* __restrict__ out)        // [T, B, 3] then [B, 3]
{
    __shared__ v4f xs[RING * CHUNK * 64];   // slot-major, lane-minor

    const int lane = threadIdx.x;
    const int b    = blockIdx.x * 64 + lane;

    // Uniform weight loads -> SGPRs
    const float w00 = Wih[0], w01 = Wih[1], w02 = Wih[2],  w03 = Wih[3];
    const float w10 = Wih[4], w11 = Wih[5], w12 = Wih[6],  w13 = Wih[7];
    const float w20 = Wih[8], w21 = Wih[9], w22 = Wih[10], w23 = Wih[11];
    const float a00 = Whh[0], a01 = Whh[1], a02 = Whh[2];
    const float a10 = Whh[3], a11 = Whh[4], a12 = Whh[5];
    const float a20 = Whh[6], a21 = Whh[7], a22 = Whh[8];
    const float bb0 = bih[0] + bhh[0];
    const float bb1 = bih[1] + bhh[1];
    const float bb2 = bih[2] + bhh[2];

    float h0r = h0[b * 3 + 0];
    float h1r = h0[b * 3 + 1];
    float h2r = h0[b * 3 + 2];

    const v4f* __restrict__ xg = (const v4f*)x;   // [T][B]
    Out3* __restrict__ ob = (Out3*)out;           // [T][B]

    // Stage one chunk: 8 x global_load_lds (16B/lane). LDS dst is the
    // wave-uniform slot base; HW writes base + lane*16 = our layout.
#define STAGE(c) do {                                                          \
        const int _slot0 = ((c) & (RING - 1)) * CHUNK;                         \
        _Pragma("unroll")                                                      \
        for (int _u = 0; _u < CHUNK; ++_u) {                                   \
            __builtin_amdgcn_global_load_lds(                                  \
                AS1c(xg + (size_t)((c) * CHUNK + _u) * BATCH + b),             \
                AS3(&xs[(_slot0 + _u) * 64]), 16, 0, 0);                       \
        }                                                                      \
    } while (0)

    // One RNN step from an LDS-resident x vector (1 ds_read_b128 + 24 VALU)
#define STEP(XV, TT) do {                                                      \
        float p0 = fmaf(w00, (XV).x, fmaf(w01, (XV).y,                         \
                   fmaf(w02, (XV).z, fmaf(w03, (XV).w, bb0))));                \
        float p1 = fmaf(w10, (XV).x, fmaf(w11, (XV).y,                         \
                   fmaf(w12, (XV).z, fmaf(w13, (XV).w, bb1))));                \
        float p2 = fmaf(w20, (XV).x, fmaf(w21, (XV).y,                         \
                   fmaf(w22, (XV).z, fmaf(w23, (XV).w, bb2))));                \
        float t0 = fmaf(a00, h0r, fmaf(a01, h1r, fmaf(a02, h2r, p0)));         \
        float t1 = fmaf(a10, h0r, fmaf(a11, h1r, fmaf(a12, h2r, p1)));         \
        float t2 = fmaf(a20, h0r, fmaf(a21, h1r, fmaf(a22, h2r, p2)));         \
        h0r = fmaxf(t0, 0.0f);                                                 \
        h1r = fmaxf(t1, 0.0f);                                                 \
        h2r = fmaxf(t2, 0.0f);                                                 \
        ob[(size_t)(TT) * BATCH + b] = Out3{h0r, h1r, h2r};                    \
    } while (0)

#define COMPUTE_CHUNK(c) do {                                                  \
        const v4f* __restrict__ _xr = &xs[(((c) & (RING - 1)) * CHUNK) * 64 + lane]; \
        _Pragma("unroll")                                                      \
        for (int _u = 0; _u < CHUNK; ++_u) {                                   \
            v4f _xv = _xr[_u * 64];   /* ds_read_b128 offset:_u*1024 */        \
            STEP(_xv, (c) * CHUNK + _u);                                       \
        }                                                                      \
    } while (0)

    // Prologue: fill 3 of 4 ring chunks
    STAGE(0);
    STAGE(1);
    STAGE(2);

    // Steady state: stage ci+3, wait until only the 3 lookahead chunks
    // (24 loads; stores newer than them are also allowed to linger up to
    // the 24 budget -- in-order vmcnt retires our chunk's loads first),
    // then compute ci.
#pragma unroll 1
    for (int ci = 0; ci <= NCHUNK - RING; ++ci) {   // 0..252, stages 3..255
        STAGE(ci + RING - 1);
        asm volatile("s_waitcnt vmcnt(24)" ::: "memory");
        COMPUTE_CHUNK(ci);
    }

    // Epilogue: last 3 chunks, full drain (cost ~1% of total)
#pragma unroll 1
    for (int ci = NCHUNK - RING + 1; ci < NCHUNK; ++ci) {  // 253..255
        asm volatile("s_waitcnt vmcnt(0)" ::: "memory");
        COMPUTE_CHUNK(ci);
    }

#undef STAGE
#undef STEP
#undef COMPUTE_CHUNK

    // h_last = outs[T-1] appended at offset T*B*3
    Out3* lastp = (Out3*)(out + (size_t)T_SEQ * BATCH * 3);
    lastp[b] = Out3{h0r, h1r, h2r};
}

extern "C" void kernel_launch(void* const* d_in, const int* in_sizes, int n_in,
                              void* d_out, int out_size, void* d_ws, size_t ws_size,
                              hipStream_t stream) {
    const float* x   = (const float*)d_in[0];
    const float* h0  = (const float*)d_in[1];
    const float* Wih = (const float*)d_in[2];
    const float* Whh = (const float*)d_in[3];
    const float* bih = (const float*)d_in[4];
    const float* bhh = (const float*)d_in[5];
    float* out = (float*)d_out;

    rnn_fused<<<BATCH / 64, 64, 0, stream>>>(x, h0, Wih, Whh, bih, bhh, out);
}

// Round 3
// 285.653 us; speedup vs baseline: 1.1217x; 1.0666x over previous
//
#include <hip/hip_runtime.h>

#define T_SEQ  2048
#define BATCH  4096
#define CHUNK  8
#define NCHUNK (T_SEQ / CHUNK)     // 256
#define XR     8                   // x-ring chunks (8 KB each = 64 KB)
#define PR     4                   // p-ring chunks (32 KB)
#define XLOOK  6                   // stage lookahead (48 loads = 48 KB in flight)
#define NITER  (NCHUNK + 2)        // consumer lags stager-pipe by 2 joint iters

typedef float v4f __attribute__((ext_vector_type(4)));
struct Out3 { float a, b, c; };

#define AS1c(p) ((const __attribute__((address_space(1))) void*)(p))
#define AS3(p)  ((__attribute__((address_space(3))) void*)(p))

// Raw barrier: must NOT use __syncthreads() -- it emits s_waitcnt vmcnt(0)
// and would drain W_stage's 48-deep load pipeline every chunk.
#define BARRIER() do {                      \
    __builtin_amdgcn_sched_barrier(0);      \
    __builtin_amdgcn_s_barrier();           \
    __builtin_amdgcn_sched_barrier(0);      \
} while (0)

// 64 blocks x 192 threads = 3 waves/block, each wave on its own SIMD.
// Wave roles (vmcnt is per-wave -- this is what defeats the compiler's
// conservative global_load_lds<->ds_read aliasing drain):
//   wid 2: stager   -- global_load_lds only, counted vmcnt(48), no ds_read
//   wid 1: p-wave   -- ds_read x, 12 FMA/step input projection, ds_write p
//   wid 0: consumer -- ds_read p, 9 FMA + 3 max recurrence, global stores
__global__ __launch_bounds__(192, 1) void rnn_fused(
    const float* __restrict__ x,    // [T, B, 4]
    const float* __restrict__ h0,   // [B, 3]
    const float* __restrict__ Wih,  // [3, 4]
    const float* __restrict__ Whh,  // [3, 3]
    const float* __restrict__ bih,  // [3]
    const float* __restrict__ bhh,  // [3]
    float* __restrict__ out)        // [T, B, 3] then [B, 3]
{
    __shared__ v4f xs[XR * CHUNK * 64];   // x ring, [chunkslot][step][lane]
    __shared__ v4f ps[PR * CHUNK * 64];   // p ring, same layout (w=pad)

    const int tid  = threadIdx.x;
    const int lane = tid & 63;
    const int wid  = tid >> 6;
    const int b    = blockIdx.x * 64 + lane;

    const v4f* __restrict__ xg = (const v4f*)x;   // [T][B]

#define STAGE(c) do {                                                          \
        const int _s0 = ((c) & (XR - 1)) * CHUNK;                              \
        _Pragma("unroll")                                                      \
        for (int _u = 0; _u < CHUNK; ++_u) {                                   \
            __builtin_amdgcn_global_load_lds(                                  \
                AS1c(xg + (size_t)((c) * CHUNK + _u) * BATCH + b),             \
                AS3(&xs[(_s0 + _u) * 64]), 16, 0, 0);                          \
        }                                                                      \
    } while (0)

    if (wid == 2) {
        // ---------------- stager ----------------
        // prologue: chunks 0..XLOOK-1 (48 loads in flight)
        for (int c = 0; c < XLOOK; ++c) STAGE(c);
#pragma unroll 1
        for (int i = 0; i < NITER; ++i) {
            if (i + XLOOK < NCHUNK) STAGE(i + XLOOK);
            // allow chunks i+1..i+6 (48 loads) outstanding; guarantees
            // chunk i fully landed in LDS before this barrier.
            asm volatile("s_waitcnt vmcnt(48)" ::: "memory");
            BARRIER();
        }
    } else if (wid == 1) {
        // ---------------- p-wave: p = W_ih @ x + b_ih + b_hh ----------------
        const float w00 = Wih[0], w01 = Wih[1], w02 = Wih[2],  w03 = Wih[3];
        const float w10 = Wih[4], w11 = Wih[5], w12 = Wih[6],  w13 = Wih[7];
        const float w20 = Wih[8], w21 = Wih[9], w22 = Wih[10], w23 = Wih[11];
        const float bb0 = bih[0] + bhh[0];
        const float bb1 = bih[1] + bhh[1];
        const float bb2 = bih[2] + bhh[2];
#pragma unroll 1
        for (int i = 0; i < NITER; ++i) {
            const int ci = i - 1;              // x(ci) landed before barrier ci
            if (ci >= 0 && ci < NCHUNK) {
                const v4f* __restrict__ xr = &xs[((ci & (XR - 1)) * CHUNK) * 64 + lane];
                v4f* __restrict__ pw = &ps[((ci & (PR - 1)) * CHUNK) * 64 + lane];
#pragma unroll
                for (int u = 0; u < CHUNK; ++u) {
                    v4f xv = xr[u * 64];
                    float p0 = fmaf(w00, xv.x, fmaf(w01, xv.y,
                               fmaf(w02, xv.z, fmaf(w03, xv.w, bb0))));
                    float p1 = fmaf(w10, xv.x, fmaf(w11, xv.y,
                               fmaf(w12, xv.z, fmaf(w13, xv.w, bb1))));
                    float p2 = fmaf(w20, xv.x, fmaf(w21, xv.y,
                               fmaf(w22, xv.z, fmaf(w23, xv.w, bb2))));
                    v4f pv; pv.x = p0; pv.y = p1; pv.z = p2; pv.w = 0.0f;
                    pw[u * 64] = pv;
                }
            }
            // publish p(ci) (and finish x reads) before the barrier
            asm volatile("s_waitcnt lgkmcnt(0)" ::: "memory");
            BARRIER();
        }
    } else {
        // ---------------- consumer: h = relu(p + W_hh @ h) ----------------
        const float a00 = Whh[0], a01 = Whh[1], a02 = Whh[2];
        const float a10 = Whh[3], a11 = Whh[4], a12 = Whh[5];
        const float a20 = Whh[6], a21 = Whh[7], a22 = Whh[8];
        float h0r = h0[b * 3 + 0];
        float h1r = h0[b * 3 + 1];
        float h2r = h0[b * 3 + 2];
        Out3* __restrict__ ob = (Out3*)out;    // [T][B]
#pragma unroll 1
        for (int i = 0; i < NITER; ++i) {
            const int cj = i - 2;              // p(cj) published before barrier cj+1
            if (cj >= 0) {
                const v4f* __restrict__ pr = &ps[((cj & (PR - 1)) * CHUNK) * 64 + lane];
                Out3* __restrict__ obase = ob + (size_t)cj * CHUNK * BATCH + b;
#pragma unroll
                for (int u = 0; u < CHUNK; ++u) {
                    v4f pv = pr[u * 64];
                    float t0 = fmaf(a00, h0r, fmaf(a01, h1r, fmaf(a02, h2r, pv.x)));
                    float t1 = fmaf(a10, h0r, fmaf(a11, h1r, fmaf(a12, h2r, pv.y)));
                    float t2 = fmaf(a20, h0r, fmaf(a21, h1r, fmaf(a22, h2r, pv.z)));
                    h0r = fmaxf(t0, 0.0f);
                    h1r = fmaxf(t1, 0.0f);
                    h2r = fmaxf(t2, 0.0f);
                    obase[(size_t)u * BATCH] = Out3{h0r, h1r, h2r};
                }
            }
            BARRIER();
        }
        // h_last appended at offset T*B*3
        Out3* lastp = (Out3*)(out + (size_t)T_SEQ * BATCH * 3);
        lastp[b] = Out3{h0r, h1r, h2r};
    }
#undef STAGE
}

extern "C" void kernel_launch(void* const* d_in, const int* in_sizes, int n_in,
                              void* d_out, int out_size, void* d_ws, size_t ws_size,
                              hipStream_t stream) {
    const float* x   = (const float*)d_in[0];
    const float* h0  = (const float*)d_in[1];
    const float* Wih = (const float*)d_in[2];
    const float* Whh = (const float*)d_in[3];
    const float* bih = (const float*)d_in[4];
    const float* bhh = (const float*)d_in[5];
    float* out = (float*)d_out;

    rnn_fused<<<BATCH / 64, 192, 0, stream>>>(x, h0, Wih, Whh, bih, bhh, out);
}

// Round 4
// 263.769 us; speedup vs baseline: 1.2148x; 1.0830x over previous
//
#include <hip/hip_runtime.h>

#define T_SEQ  2048
#define BATCH  4096
#define CHUNK  16                  // timesteps per pipeline stage
#define NCHUNK (T_SEQ / CHUNK)     // 128
#define XR     6                   // x-ring slots (16 KB each) = 96 KB
#define PR     2                   // p-ring slots (16 KB each) = 32 KB
#define NS     6                   // stager waves
#define LOOK   4                   // stage lookahead in iterations (~2000 cyc)
#define NITER  (NCHUNK + 2)        // consumer lags pipe by 2 joint iters

typedef float v4f __attribute__((ext_vector_type(4)));
struct Out3 { float a, b, c; };

#define AS1c(p) ((const __attribute__((address_space(1))) void*)(p))
#define AS3(p)  ((__attribute__((address_space(3))) void*)(p))

// Inline-asm barrier: opaque to the compiler's waitcnt legalizer, so it
// CANNOT inject "s_waitcnt vmcnt(0)" before it (the suspected R3 killer —
// global_load_lds writes LDS, and the builtin barrier's LDS semantics let
// the compiler conservatively drain the whole load pipeline every iter).
#define BARRIER() do {                              \
    __builtin_amdgcn_sched_barrier(0);              \
    asm volatile("s_barrier" ::: "memory");         \
    __builtin_amdgcn_sched_barrier(0);              \
} while (0)

// 64 blocks x 512 threads = 8 waves/block on one CU (2 per SIMD; stagers
// are barrier-idle so consumer/p-wave effectively own their SIMDs).
//   wid 0      : consumer -- ds_read p, 9 FMA + 3 max recurrence, store out
//   wid 1      : p-wave   -- ds_read x, 12 FMA projection, ds_write p
//   wid 2..7   : stagers  -- stager s owns chunks c == s (mod 6);
//                global_load_lds 4 iters ahead, <=1 chunk outstanding each,
//                so its vmcnt(0) waits only for the chunk that is due.
__global__ __launch_bounds__(512, 1) void rnn_fused(
    const float* __restrict__ x,    // [T, B, 4]
    const float* __restrict__ h0,   // [B, 3]
    const float* __restrict__ Wih,  // [3, 4]
    const float* __restrict__ Whh,  // [3, 3]
    const float* __restrict__ bih,  // [3]
    const float* __restrict__ bhh,  // [3]
    float* __restrict__ out)        // [T, B, 3] then [B, 3]
{
    __shared__ v4f xs[XR * CHUNK * 64];   // 96 KB: [slot][step][lane]
    __shared__ v4f ps[PR * CHUNK * 64];   // 32 KB: [slot][step][lane]

    const int tid  = threadIdx.x;
    const int lane = tid & 63;
    const int wid  = tid >> 6;
    const int b    = blockIdx.x * 64 + lane;

    const v4f* __restrict__ xg = (const v4f*)x;   // [T][B]

#define STAGE(c) do {                                                          \
        const int _s0 = ((c) % XR) * CHUNK;                                    \
        _Pragma("unroll")                                                      \
        for (int _u = 0; _u < CHUNK; ++_u) {                                   \
            __builtin_amdgcn_global_load_lds(                                  \
                AS1c(xg + (size_t)((c) * CHUNK + _u) * BATCH + b),             \
                AS3(&xs[(_s0 + _u) * 64]), 16, 0, 0);                          \
        }                                                                      \
    } while (0)

    if (wid >= 2) {
        // ---------------- stagers ----------------
        const int s = wid - 2;                      // 0..5
        if (s < LOOK) STAGE(s);                     // prologue chunks 0..3
        int nstage = (s < LOOK) ? (s + NS) : s;     // next chunk to issue
        int nwait  = s;                             // next barrier where my chunk is due
#pragma unroll 1
        for (int i = 0; i < NITER; ++i) {
            if (nstage < NCHUNK && i + LOOK == nstage) { STAGE(nstage); nstage += NS; }
            if (i == nwait) {
                asm volatile("s_waitcnt vmcnt(0)" ::: "memory");  // only my due chunk
                nwait += NS;
            }
            BARRIER();
        }
    } else if (wid == 1) {
        // ---------------- p-wave: p = W_ih @ x + b_ih + b_hh ----------------
        const float w00 = Wih[0], w01 = Wih[1], w02 = Wih[2],  w03 = Wih[3];
        const float w10 = Wih[4], w11 = Wih[5], w12 = Wih[6],  w13 = Wih[7];
        const float w20 = Wih[8], w21 = Wih[9], w22 = Wih[10], w23 = Wih[11];
        const float bb0 = bih[0] + bhh[0];
        const float bb1 = bih[1] + bhh[1];
        const float bb2 = bih[2] + bhh[2];
#pragma unroll 1
        for (int i = 0; i < NITER; ++i) {
            const int cp = i - 1;                  // x(cp) landed before barrier cp
            if (cp >= 0 && cp < NCHUNK) {
                const v4f* __restrict__ xr = &xs[((cp % XR) * CHUNK) * 64 + lane];
                v4f* __restrict__ pw = &ps[((cp & (PR - 1)) * CHUNK) * 64 + lane];
#pragma unroll
                for (int u = 0; u < CHUNK; ++u) {
                    v4f xv = xr[u * 64];
                    float p0 = fmaf(w00, xv.x, fmaf(w01, xv.y,
                               fmaf(w02, xv.z, fmaf(w03, xv.w, bb0))));
                    float p1 = fmaf(w10, xv.x, fmaf(w11, xv.y,
                               fmaf(w12, xv.z, fmaf(w13, xv.w, bb1))));
                    float p2 = fmaf(w20, xv.x, fmaf(w21, xv.y,
                               fmaf(w22, xv.z, fmaf(w23, xv.w, bb2))));
                    v4f pv; pv.x = p0; pv.y = p1; pv.z = p2; pv.w = 0.0f;
                    pw[u * 64] = pv;
                }
                // publish p(cp) before the barrier
                asm volatile("s_waitcnt lgkmcnt(0)" ::: "memory");
            }
            BARRIER();
        }
    } else {
        // ---------------- consumer: h = relu(p + W_hh @ h) ----------------
        const float a00 = Whh[0], a01 = Whh[1], a02 = Whh[2];
        const float a10 = Whh[3], a11 = Whh[4], a12 = Whh[5];
        const float a20 = Whh[6], a21 = Whh[7], a22 = Whh[8];
        float h0r = h0[b * 3 + 0];
        float h1r = h0[b * 3 + 1];
        float h2r = h0[b * 3 + 2];
        Out3* __restrict__ ob = (Out3*)out;        // [T][B]
#pragma unroll 1
        for (int i = 0; i < NITER; ++i) {
            const int cc = i - 2;                  // p(cc) published before barrier cc+1
            if (cc >= 0) {
                const v4f* __restrict__ pr = &ps[((cc & (PR - 1)) * CHUNK) * 64 + lane];
                Out3* __restrict__ obase = ob + (size_t)cc * CHUNK * BATCH + b;
#pragma unroll
                for (int u = 0; u < CHUNK; ++u) {
                    v4f pv = pr[u * 64];
                    float t0 = fmaf(a00, h0r, fmaf(a01, h1r, fmaf(a02, h2r, pv.x)));
                    float t1 = fmaf(a10, h0r, fmaf(a11, h1r, fmaf(a12, h2r, pv.y)));
                    float t2 = fmaf(a20, h0r, fmaf(a21, h1r, fmaf(a22, h2r, pv.z)));
                    h0r = fmaxf(t0, 0.0f);
                    h1r = fmaxf(t1, 0.0f);
                    h2r = fmaxf(t2, 0.0f);
                    obase[(size_t)u * BATCH] = Out3{h0r, h1r, h2r};
                }
            }
            BARRIER();
        }
        // h_last appended at offset T*B*3
        Out3* lastp = (Out3*)(out + (size_t)T_SEQ * BATCH * 3);
        lastp[b] = Out3{h0r, h1r, h2r};
    }
#undef STAGE
}

extern "C" void kernel_launch(void* const* d_in, const int* in_sizes, int n_in,
                              void* d_out, int out_size, void* d_ws, size_t ws_size,
                              hipStream_t stream) {
    const float* x   = (const float*)d_in[0];
    const float* h0  = (const float*)d_in[1];
    const float* Wih = (const float*)d_in[2];
    const float* Whh = (const float*)d_in[3];
    const float* bih = (const float*)d_in[4];
    const float* bhh = (const float*)d_in[5];
    float* out = (float*)d_out;

    rnn_fused<<<BATCH / 64, 512, 0, stream>>>(x, h0, Wih, Whh, bih, bhh, out);
}

// Round 5
// 250.731 us; speedup vs baseline: 1.2780x; 1.0520x over previous
//
#include <hip/hip_runtime.h>

#define T_SEQ   2048
#define BATCH   4096
#define BPB     16                  // batch elements per block
#define NBLK    (BATCH / BPB)       // 256 blocks -> 1 per CU, all 8 XCDs
#define CHUNK   64                  // timesteps per pipeline iteration
#define NCHUNK  (T_SEQ / CHUNK)     // 32
#define XR      4                   // x-ring slots (16 KB each) = 64 KB LDS
#define NS      3                   // stager waves
#define NITER   (NCHUNK + 1)        // compute lags pipe by 1 iteration

typedef float v4f __attribute__((ext_vector_type(4)));

#define AS1c(p) ((const __attribute__((address_space(1))) void*)(p))
#define AS3(p)  ((__attribute__((address_space(3))) void*)(p))

// Inline-asm barrier: opaque to the waitcnt legalizer (no injected vmcnt(0)).
#define BARRIER() do {                              \
    __builtin_amdgcn_sched_barrier(0);              \
    asm volatile("s_barrier" ::: "memory");         \
    __builtin_amdgcn_sched_barrier(0);              \
} while (0)

// DPP quad broadcast of a float from quad-lane k (k=0,1,2)
#define QBCAST(hf, pat) \
    __builtin_bit_cast(float, __builtin_amdgcn_mov_dpp( \
        __builtin_bit_cast(int, (hf)), (pat), 0xF, 0xF, true))

// 256 blocks x 256 threads (4 waves). Per-CU HBM delivery is walled at
// ~8 B/cyc (R1/R3/R4: 5/6.8/8.25 regardless of MLP depth), so the batch is
// spread over ALL 256 CUs: 16 batch/block, 4 lanes per batch element.
//   wid 0    : compute -- lane 4*bi+j owns h_j of batch bi; h broadcast
//              within the quad via v_mov_dpp; lane j=3 masked off.
//   wid 1..3 : stagers -- stager s owns chunks c == s (mod 3), issues 2
//              iterations ahead, <=1 chunk outstanding -> its vmcnt(0)
//              waits only the due chunk.
__global__ __launch_bounds__(256, 1) void rnn_fused(
    const float* __restrict__ x,    // [T, B, 4]
    const float* __restrict__ h0,   // [B, 3]
    const float* __restrict__ Wih,  // [3, 4]
    const float* __restrict__ Whh,  // [3, 3]
    const float* __restrict__ bih,  // [3]
    const float* __restrict__ bhh,  // [3]
    float* __restrict__ out)        // [T, B, 3] then [B, 3]
{
    __shared__ v4f xs[XR * CHUNK * BPB];   // 64 KB: [slot][tt][bi]

    const int tid  = threadIdx.x;
    const int lane = tid & 63;
    const int wid  = tid >> 6;
    const int b0   = blockIdx.x * BPB;

    if (wid > 0) {
        // ---------------- stagers ----------------
        const int s = wid - 1;                          // 0..2
        const v4f* __restrict__ xg = (const v4f*)x;     // [T][B]
        // lane l sources x[t0 + l/16][b0 + l%16]; LDS gets base + l*16
        const int vlo = (lane >> 4) * BATCH + b0 + (lane & 15);

#define STAGE(c) do {                                                          \
        const int _slot = ((c) & (XR - 1)) * (CHUNK * BPB);                    \
        _Pragma("unroll")                                                      \
        for (int _g = 0; _g < CHUNK / 4; ++_g) {                               \
            __builtin_amdgcn_global_load_lds(                                  \
                AS1c(xg + ((size_t)(c) * CHUNK + _g * 4) * BATCH + vlo),       \
                AS3(&xs[_slot + _g * (4 * BPB)]), 16, 0, 0);                   \
        }                                                                      \
    } while (0)

        if (s == 0) STAGE(0);                           // prologue
        if (s == 1) STAGE(1);
#pragma unroll 1
        for (int i = 0; i < NITER; ++i) {
            const int ci = i + 2;                       // issue 2 iters ahead
            if (ci < NCHUNK && (ci % NS) == s) STAGE(ci);
            if (i < NCHUNK && (i % NS) == s)
                asm volatile("s_waitcnt vmcnt(0)" ::: "memory");
            BARRIER();
        }
#undef STAGE
    } else {
        // ---------------- compute wave ----------------
        const int bi = lane >> 2;       // local batch 0..15
        const int j  = lane & 3;        // output row 0..2; 3 = spare
        const int jj = (j < 3) ? j : 2; // lane 3 duplicates row 2 (never used)

        const float w0 = Wih[jj * 4 + 0], w1 = Wih[jj * 4 + 1];
        const float w2 = Wih[jj * 4 + 2], w3 = Wih[jj * 4 + 3];
        const float a0 = Whh[jj * 3 + 0], a1 = Whh[jj * 3 + 1];
        const float a2 = Whh[jj * 3 + 2];
        const float bb = bih[jj] + bhh[jj];

        float h = h0[(b0 + bi) * 3 + jj];
        const size_t ooff = (size_t)(b0 + bi) * 3 + j;  // per-lane out column

#pragma unroll 1
        for (int i = 0; i < NITER; ++i) {
            const int c = i - 1;        // chunk c guaranteed in LDS after barrier c
            if (c >= 0 && j < 3) {      // one exec-mask toggle per chunk
                const v4f* __restrict__ xr = &xs[(c & (XR - 1)) * (CHUNK * BPB) + bi];
                float* __restrict__ op = out + (size_t)c * CHUNK * (BATCH * 3) + ooff;
#pragma unroll
                for (int tt = 0; tt < CHUNK; ++tt) {
                    v4f xv = xr[tt * BPB];              // quad-uniform ds_read_b128
                    float p = fmaf(w0, xv.x, fmaf(w1, xv.y,
                              fmaf(w2, xv.z, fmaf(w3, xv.w, bb))));
                    float g0 = QBCAST(h, 0x00);         // h0 from quad lane 0
                    float g1 = QBCAST(h, 0x55);         // h1 from quad lane 1
                    float g2 = QBCAST(h, 0xAA);         // h2 from quad lane 2
                    float t0 = fmaf(a0, g0, fmaf(a1, g1, fmaf(a2, g2, p)));
                    h = fmaxf(t0, 0.0f);
                    op[(size_t)tt * (BATCH * 3)] = h;
                }
            }
            BARRIER();
        }
        // h_last appended at offset T*B*3
        if (j < 3)
            out[(size_t)T_SEQ * BATCH * 3 + ooff] = h;
    }
}

extern "C" void kernel_launch(void* const* d_in, const int* in_sizes, int n_in,
                              void* d_out, int out_size, void* d_ws, size_t ws_size,
                              hipStream_t stream) {
    const float* x   = (const float*)d_in[0];
    const float* h0  = (const float*)d_in[1];
    const float* Wih = (const float*)d_in[2];
    const float* Whh = (const float*)d_in[3];
    const float* bih = (const float*)d_in[4];
    const float* bhh = (const float*)d_in[5];
    float* out = (float*)d_out;

    rnn_fused<<<NBLK, 256, 0, stream>>>(x, h0, Wih, Whh, bih, bhh, out);
}

// Round 7
// 237.888 us; speedup vs baseline: 1.3470x; 1.0540x over previous
//
#include <hip/hip_runtime.h>

#define T_SEQ   2048
#define BATCH   4096
#define BPB     16                  // batch elements per block
#define NBLK    (BATCH / BPB)       // 256 blocks, one per CU
#define CHUNK   64                  // timesteps per pipeline iteration
#define NCHUNK  (T_SEQ / CHUNK)     // 32
#define XR      4                   // x-ring slots  (16 KB) = 64 KB
#define NP      2                   // p-ring slots  (16 KB) = 32 KB
#define NO      2                   // h-out slots   (12 KB) = 24 KB
#define NS      3                   // stager waves
#define NITER   (NCHUNK + 3)        // writer lags pipe by 3 iterations

typedef float v4f __attribute__((ext_vector_type(4)));

#define AS1c(p) ((const __attribute__((address_space(1))) void*)(p))
#define AS3(p)  ((__attribute__((address_space(3))) void*)(p))

// Inline-asm barrier: opaque to the waitcnt legalizer (no injected vmcnt(0)).
#define BARRIER() do {                              \
    __builtin_amdgcn_sched_barrier(0);              \
    asm volatile("s_barrier" ::: "memory");         \
    __builtin_amdgcn_sched_barrier(0);              \
} while (0)

#define LGKM0() asm volatile("s_waitcnt lgkmcnt(0)" ::: "memory")

// DPP quad broadcast of a float from quad-lane k (patterns 0x00/0x55/0xAA)
#define QBCAST(hf, pat) \
    __builtin_bit_cast(float, __builtin_amdgcn_mov_dpp( \
        __builtin_bit_cast(int, (hf)), (pat), 0xF, 0xF, true))

// 256 blocks x 384 threads (6 waves). R4/R5 showed the serial consumer wave
// itself at ~100+ cyc/step (shallow compiler LDS pipelining + global stores
// on the serial wave). R6 strips the consumer to LDS-only with an explicit
// 8-deep p prefetch rotation; p-compute and global stores move to helpers.
//   wid 0    : consumer -- ds_read p, 3 DPP + 3 FMA + max, ds_write h
//   wid 1    : p-wave   -- ds_read x (b128), 12 FMA, ds_write p (b128)
//   wid 2..4 : stagers  -- chunk c owned by stager c%3; issued 2 iters
//              ahead; <=1 chunk outstanding -> vmcnt(0) waits only its due.
//   wid 5    : writer   -- ds_read h-out ring, coalesced dwordx4 stores
__global__ __launch_bounds__(384, 1) void rnn_fused(
    const float* __restrict__ x,    // [T, B, 4]
    const float* __restrict__ h0,   // [B, 3]
    const float* __restrict__ Wih,  // [3, 4]
    const float* __restrict__ Whh,  // [3, 3]
    const float* __restrict__ bih,  // [3]
    const float* __restrict__ bhh,  // [3]
    float* __restrict__ out)        // [T, B, 3] then [B, 3]
{
    __shared__ v4f  xs[XR * CHUNK * BPB];    // 64 KB [slot][tt][bi]
    __shared__ v4f  ps[NP * CHUNK * BPB];    // 32 KB [slot][tt][bi] = p0,p1,p2,pad
    __shared__ float hs[NO * CHUNK * 48];    // 24 KB [slot][tt*48 + bi*3 + j]

    const int tid  = threadIdx.x;
    const int lane = tid & 63;
    const int wid  = tid >> 6;
    const int b0   = blockIdx.x * BPB;

    if (wid >= 2 && wid <= 4) {
        // ---------------- stagers ----------------
        const int s = wid - 2;                          // 0..2
        const v4f* __restrict__ xg = (const v4f*)x;     // [T][B]
        const int vlo = (lane >> 4) * BATCH + b0 + (lane & 15);  // 4 t x 16 bi

#define STAGE(c) do {                                                          \
        const int _s0 = ((c) & (XR - 1)) * (CHUNK * BPB);                      \
        _Pragma("unroll")                                                      \
        for (int _g = 0; _g < CHUNK / 4; ++_g) {                               \
            __builtin_amdgcn_global_load_lds(                                  \
                AS1c(xg + ((size_t)(c) * CHUNK + _g * 4) * BATCH + vlo),       \
                AS3(&xs[_s0 + _g * (4 * BPB)]), 16, 0, 0);                     \
        }                                                                      \
    } while (0)

        if (s == 0) STAGE(0);                           // prologue
        if (s == 1) STAGE(1);
#pragma unroll 1
        for (int i = 0; i < NITER; ++i) {
            const int ci = i + 2;
            if (ci < NCHUNK && (ci % NS) == s) STAGE(ci);
            if (i < NCHUNK && (i % NS) == s)
                asm volatile("s_waitcnt vmcnt(0)" ::: "memory");
            BARRIER();
        }
#undef STAGE
    } else if (wid == 1) {
        // ---------------- p-wave: p[t][bi] = W_ih @ x + b ----------------
        const int ts = lane >> 4;                       // 0..3 (t within group)
        const int bi = lane & 15;
        const float w00 = Wih[0], w01 = Wih[1], w02 = Wih[2],  w03 = Wih[3];
        const float w10 = Wih[4], w11 = Wih[5], w12 = Wih[6],  w13 = Wih[7];
        const float w20 = Wih[8], w21 = Wih[9], w22 = Wih[10], w23 = Wih[11];
        const float bb0 = bih[0] + bhh[0];
        const float bb1 = bih[1] + bhh[1];
        const float bb2 = bih[2] + bhh[2];
#pragma unroll 1
        for (int i = 0; i < NITER; ++i) {
            const int c = i - 1;
            if (c >= 0 && c < NCHUNK) {
                const v4f* __restrict__ xb = &xs[((c & (XR - 1)) * CHUNK + ts) * BPB + bi];
                v4f* __restrict__ pw = &ps[((c & (NP - 1)) * CHUNK + ts) * BPB + bi];
                // 2-deep rotation; reads past slot end land in ps (harmless)
                v4f xa = xb[0];
                v4f xc = xb[64];                         // g=1 (4 t = 64 v4f)
#pragma unroll
                for (int g = 0; g < 16; ++g) {
                    v4f xv = xa; xa = xc;
                    xc = xb[(g + 2) * 64];               // OOB-slot: garbage, unused
                    float p0 = fmaf(w00, xv.x, fmaf(w01, xv.y,
                               fmaf(w02, xv.z, fmaf(w03, xv.w, bb0))));
                    float p1 = fmaf(w10, xv.x, fmaf(w11, xv.y,
                               fmaf(w12, xv.z, fmaf(w13, xv.w, bb1))));
                    float p2 = fmaf(w20, xv.x, fmaf(w21, xv.y,
                               fmaf(w22, xv.z, fmaf(w23, xv.w, bb2))));
                    v4f pv; pv.x = p0; pv.y = p1; pv.z = p2; pv.w = p2;
                    pw[g * 64] = pv;
                }
                LGKM0();                                 // publish p(c)
            }
            BARRIER();
        }
    } else if (wid == 0) {
        // ---------------- consumer: h = relu(p + W_hh @ h) ----------------
        const int bi = lane >> 2;                        // 0..15
        const int j  = lane & 3;                         // 0..2 used, 3 spare
        const int jj = (j < 3) ? j : 2;
        const float a0 = Whh[jj * 3 + 0], a1 = Whh[jj * 3 + 1], a2 = Whh[jj * 3 + 2];
        float h = h0[(b0 + bi) * 3 + jj];

#pragma unroll 1
        for (int i = 0; i < NITER; ++i) {
            const int c = i - 2;
            if (c >= 0 && c < NCHUNK && j < 3) {
                const float* __restrict__ pb =
                    (const float*)&ps[(c & (NP - 1)) * CHUNK * BPB] + bi * 4 + jj;
                float* __restrict__ hb = &hs[(c & (NO - 1)) * CHUNK * 48 + bi * 3 + j];
                // 8-deep named prefetch rotation (reads past slot are harmless)
                float q0 = pb[0 * 64], q1 = pb[1 * 64], q2 = pb[2 * 64], q3 = pb[3 * 64];
                float q4 = pb[4 * 64], q5 = pb[5 * 64], q6 = pb[6 * 64], q7 = pb[7 * 64];
#define STEPC(TT, Q) do {                                                      \
                float g2 = QBCAST(h, 0xAA);                                    \
                float g1 = QBCAST(h, 0x55);                                    \
                float g0 = QBCAST(h, 0x00);                                    \
                float t0 = fmaf(a0, g0, fmaf(a1, g1, fmaf(a2, g2, (Q))));      \
                h = fmaxf(t0, 0.0f);                                           \
                hb[(TT) * 48] = h;                                             \
                Q = pb[((TT) + 8) * 64];                                       \
            } while (0)
#pragma unroll
                for (int t8 = 0; t8 < CHUNK; t8 += 8) {
                    STEPC(t8 + 0, q0); STEPC(t8 + 1, q1);
                    STEPC(t8 + 2, q2); STEPC(t8 + 3, q3);
                    STEPC(t8 + 4, q4); STEPC(t8 + 5, q5);
                    STEPC(t8 + 6, q6); STEPC(t8 + 7, q7);
                }
#undef STEPC
                LGKM0();                                 // publish h-out(c)
            }
            BARRIER();
        }
        // h_last appended at offset T*B*3
        if (j < 3)
            out[(size_t)T_SEQ * BATCH * 3 + (size_t)(b0 + bi) * 3 + j] = h;
    } else {
        // ---------------- writer: LDS h-out -> global, coalesced ----------
        unsigned lt = (unsigned)(lane * 4) / 48;         // t within chunk
        unsigned r  = (unsigned)(lane * 4) - lt * 48;    // float within row
#pragma unroll 1
        for (int i = 0; i < NITER; ++i) {
            const int c = i - 3;
            if (c >= 0 && c < NCHUNK) {
                const float* __restrict__ hb = &hs[(c & (NO - 1)) * CHUNK * 48];
                char* __restrict__ oc = (char*)(out + (size_t)c * CHUNK * (BATCH * 3)
                                                + (size_t)b0 * 3);
                unsigned ltw = lt, rw = r;
#pragma unroll
                for (int w = 0; w < 12; ++w) {
                    v4f v = *(const v4f*)&hb[w * 256 + lane * 4];
                    *(v4f*)(oc + (size_t)ltw * (BATCH * 3 * 4) + rw * 4) = v;
                    rw += 16; ltw += 5;
                    if (rw >= 48) { rw -= 48; ltw += 1; }
                }
                LGKM0();                                 // reads done before slot reuse
            }
            BARRIER();
        }
    }
}

extern "C" void kernel_launch(void* const* d_in, const int* in_sizes, int n_in,
                              void* d_out, int out_size, void* d_ws, size_t ws_size,
                              hipStream_t stream) {
    const float* x   = (const float*)d_in[0];
    const float* h0  = (const float*)d_in[1];
    const float* Wih = (const float*)d_in[2];
    const float* Whh = (const float*)d_in[3];
    const float* bih = (const float*)d_in[4];
    const float* bhh = (const float*)d_in[5];
    float* out = (float*)d_out;

    rnn_fused<<<NBLK, 384, 0, stream>>>(x, h0, Wih, Whh, bih, bhh, out);
}